// Round 14
// baseline (1472.005 us; speedup 1.0000x reference)
//
#include <hip/hip_runtime.h>

#define NN 50000
#define NE 800000
#define MAXC 100000
#define EBLK 1024     // grid-stride; occupancy-bound residency
#define SCB ((NN + 255) / 256)   // scan blocks = 196

__device__ __forceinline__ float silu_f(float v) {
    return v * __builtin_amdgcn_rcpf(1.f + __expf(-v));
}

typedef __bf16 bf16;
typedef bf16 v8bf __attribute__((ext_vector_type(8)));
typedef float v4f __attribute__((ext_vector_type(4)));

#define UNPACK8(dstv, ptr) { \
    float4 _a = reinterpret_cast<const float4*>(ptr)[0]; \
    float4 _b = reinterpret_cast<const float4*>(ptr)[1]; \
    dstv[0]=_a.x; dstv[1]=_a.y; dstv[2]=_a.z; dstv[3]=_a.w; \
    dstv[4]=_b.x; dstv[5]=_b.y; dstv[6]=_b.z; dstv[7]=_b.w; }

// ---------------------------------------------------------------- fused weight prep (8 tensors)
// hi/lo bf16 split in MFMA B-fragment order: dst ((kh*4+g)*Ncol+col)*8+b, k=kh*32+g*8+b
__global__ __launch_bounds__(256) void k_prep_all(
    const float* __restrict__ eW1, const float* __restrict__ dW1,
    const float* __restrict__ eW2, const float* __restrict__ dW2,
    const float* __restrict__ eN1, const float* __restrict__ dN1,
    const float* __restrict__ eN2, const float* __restrict__ dN2,
    const float* __restrict__ Wlat, const float* __restrict__ Wup,
    const float* __restrict__ Wemb, const float* __restrict__ Wout,
    bf16* __restrict__ We1h, bf16* __restrict__ We1l,
    bf16* __restrict__ We2h, bf16* __restrict__ We2l,
    bf16* __restrict__ Wn1h, bf16* __restrict__ Wn1l,
    bf16* __restrict__ Wn2h, bf16* __restrict__ Wn2l,
    bf16* __restrict__ Wlh,  bf16* __restrict__ Wll,
    bf16* __restrict__ Wuh,  bf16* __restrict__ Wul,
    bf16* __restrict__ Wembh, bf16* __restrict__ Wembl,
    bf16* __restrict__ Wouth, bf16* __restrict__ Woutl)
{
    int t = blockIdx.x * 256 + threadIdx.x;   // total 105472 = 412 blocks
    float w; int di; bf16 *Wh, *Wl;
    if (t < 98304) {
        const float *encW, *decW; int K, stride; int r;
        if (t < 32768)      { r = t;         encW = eW1; decW = dW1; K = 128; stride = 129 * 64; Wh = We1h; Wl = We1l; }
        else if (t < 49152) { r = t - 32768; encW = eW2; decW = dW2; K = 64;  stride = 64 * 64;  Wh = We2h; Wl = We2l; }
        else if (t < 81920) { r = t - 49152; encW = eN1; decW = dN1; K = 128; stride = 128 * 64; Wh = Wn1h; Wl = Wn1l; }
        else                { r = t - 81920; encW = eN2; decW = dN2; K = 64;  stride = 64 * 64;  Wh = Wn2h; Wl = Wn2l; }
        int per = K * 64;
        int li = r / per, rr = r - li * per;
        int k = rr >> 6, col = rr & 63;
        const float* Wsrc = (li < 2 ? encW : decW) + (li & 1) * stride;
        w = Wsrc[k * 64 + col];
        int kh = k >> 5, gg = (k >> 3) & 3, b = k & 7;
        di = li * per + (((kh * 4 + gg) * 64 + col) * 8 + b);
    } else if (t < 100352) {
        int r = t - 98304;                    // Wlat: K=64, Ncol=32
        int k = r >> 5, col = r & 31;
        w = Wlat[k * 32 + col];
        int kh = k >> 5, gg = (k >> 3) & 3, b = k & 7;
        di = ((kh * 4 + gg) * 32 + col) * 8 + b;
        Wh = Wlh; Wl = Wll;
    } else if (t < 102400) {
        int r = t - 100352;                   // Wup: K=32, Ncol=64
        int k = r >> 6, col = r & 63;
        w = Wup[k * 64 + col];
        int gg = (k >> 3) & 3, b = k & 7;
        di = (gg * 64 + col) * 8 + b;
        Wh = Wuh; Wl = Wul;
    } else if (t < 104448) {
        int r = t - 102400;                   // Wemb: K=16 (padded to 32), Ncol=64
        int gg = r >> 9, col = (r >> 3) & 63, b = r & 7;
        int k = gg * 8 + b;
        w = (k < 16) ? Wemb[k * 64 + col] : 0.f;
        di = r;                               // (gg*64+col)*8+b
        Wh = Wembh; Wl = Wembl;
    } else if (t < 105472) {
        int r = t - 104448;                   // Wout: K=64, Ncol=16
        int kh4g = r >> 7, col = (r >> 3) & 15, b = r & 7;
        int kh = kh4g >> 2, gg = kh4g & 3;
        int k = kh * 32 + gg * 8 + b;
        w = Wout[k * 16 + col];
        di = r;                               // ((kh*4+gg)*16+col)*8+b
        Wh = Wouth; Wl = Woutl;
    } else return;
    bf16 hi = (bf16)w;
    Wh[di] = hi; Wl[di] = (bf16)(w - (float)hi);
}

// ---------------------------------------------------------------- CSR build (by dst)
__global__ __launch_bounds__(256) void k_hist(const int* __restrict__ dst, int* __restrict__ cnt)
{
    int e = blockIdx.x * 256 + threadIdx.x;
    if (e < NE) atomicAdd(&cnt[dst[e]], 1);
}

__global__ __launch_bounds__(256) void k_blocksum(
    const int* __restrict__ cnt, int* __restrict__ bsum)
{
    int b = blockIdx.x, tid = threadIdx.x;
    int i = b * 256 + tid;
    int deg = (i < NN) ? cnt[i] : 0;
    int chk = (deg + 15) >> 4;
#pragma unroll
    for (int d = 1; d < 64; d <<= 1) { deg += __shfl_xor(deg, d); chk += __shfl_xor(chk, d); }
    __shared__ int sd[4], sc[4];
    int wv = tid >> 6;
    if ((tid & 63) == 0) { sd[wv] = deg; sc[wv] = chk; }
    __syncthreads();
    if (tid == 0) {
        bsum[b] = sd[0] + sd[1] + sd[2] + sd[3];
        bsum[SCB + b] = sc[0] + sc[1] + sc[2] + sc[3];
    }
}

__global__ __launch_bounds__(256) void k_scanbase(
    const int* __restrict__ bsum, int* __restrict__ bbase, int* __restrict__ ncptr)
{
    __shared__ int s[256], s2[256];
    int tid = threadIdx.x;
    int v  = (tid < SCB) ? bsum[tid] : 0;
    int v2 = (tid < SCB) ? bsum[SCB + tid] : 0;
    s[tid] = v; s2[tid] = v2;
    __syncthreads();
    for (int d = 1; d < 256; d <<= 1) {
        int u  = (tid >= d) ? s[tid - d] : 0;
        int u2 = (tid >= d) ? s2[tid - d] : 0;
        __syncthreads();
        s[tid] += u; s2[tid] += u2;
        __syncthreads();
    }
    if (tid < SCB) {
        bbase[tid]       = s[tid] - v;
        bbase[SCB + tid] = s2[tid] - v2;
    }
    if (tid == 255) *ncptr = s2[SCB - 1];
}

// phase 3: per-block local scan + base apply -> off, cur; fused chunk-meta fill
__global__ __launch_bounds__(256) void k_applyscan(
    int* __restrict__ cnt, const int* __restrict__ bbase,
    int* __restrict__ off, int* __restrict__ cur, int2* __restrict__ cpair)
{
    int b = blockIdx.x, tid = threadIdx.x;
    int i = b * 256 + tid;
    int deg = (i < NN) ? cnt[i] : 0;
    int chk = (deg + 15) >> 4;
    __shared__ int s[256], s2[256];
    s[tid] = deg; s2[tid] = chk;
    __syncthreads();
    for (int d = 1; d < 256; d <<= 1) {
        int u  = (tid >= d) ? s[tid - d] : 0;
        int u2 = (tid >= d) ? s2[tid - d] : 0;
        __syncthreads();
        s[tid] += u; s2[tid] += u2;
        __syncthreads();
    }
    if (i < NN) {
        int o = bbase[b] + s[tid] - deg;
        off[i] = o; cur[i] = o;
        int co = bbase[SCB + b] + s2[tid] - chk;
        int e = o + deg;
        int single = (deg <= 16) ? (1 << 25) : 0;
        for (int eb = o; eb < e; eb += 16) {
            int c = min(e - eb, 16);
            cpair[co++] = make_int2(i, eb | (c << 20) | single);
        }
    }
    if (i == 0) off[NN] = NE;
}

__global__ __launch_bounds__(256) void k_scatter(
    const int* __restrict__ dst, const int* __restrict__ srcArr,
    int* __restrict__ cur, int* __restrict__ srcp)
{
    int e = blockIdx.x * 256 + threadIdx.x;
    if (e < NE) { int p = atomicAdd(&cur[dst[e]], 1); srcp[p] = srcArr[e]; }
}

// ------------------------------- L0: embed (MFMA, K=16 padded) + P/Q + zero agg/dxb + x init
__global__ __launch_bounds__(256) void k_pq_mfma(
    const float* __restrict__ h_in, const float* __restrict__ x_in,
    const bf16* __restrict__ Wembh, const bf16* __restrict__ Wembl, const float* __restrict__ bemb,
    float* __restrict__ h, float* __restrict__ xp,
    const bf16* __restrict__ We1h, const bf16* __restrict__ We1l,
    const float* __restrict__ be1,
    float* __restrict__ P, float* __restrict__ Q,
    float* __restrict__ agg, float* __restrict__ dxb)
{
    __shared__ float sh[4][16][68];
    const int wv = threadIdx.x >> 6, lane = threadIdx.x & 63;
    const int g = lane >> 4, l15 = lane & 15;
    const int n0 = (blockIdx.x * 4 + wv) * 16;
    if (n0 >= NN) return;
    const int nrow = n0 + l15;

    // ---- embed: h = h_in @ W_emb + b_emb (A-frag k = g*8+b, valid k<16 -> g<2)
    v8bf Eh, El;
    if (g < 2) {
        float ev[8];
        UNPACK8(ev, h_in + nrow * 16 + g * 8);
#pragma unroll
        for (int b = 0; b < 8; b++) {
            bf16 hi = (bf16)ev[b];
            Eh[b] = hi; El[b] = (bf16)(ev[b] - (float)hi);
        }
    } else {
#pragma unroll
        for (int b = 0; b < 8; b++) { Eh[b] = (bf16)0.f; El[b] = (bf16)0.f; }
    }
    {
        const v8bf* BEh = reinterpret_cast<const v8bf*>(Wembh);
        const v8bf* BEl = reinterpret_cast<const v8bf*>(Wembl);
#pragma unroll
        for (int nt = 0; nt < 4; nt++) {
            v4f a = {0.f, 0.f, 0.f, 0.f};
            int fi = g * 64 + l15 + 16 * nt;
            v8bf bh = BEh[fi], bl_ = BEl[fi];
            a = __builtin_amdgcn_mfma_f32_16x16x32_bf16(Eh, bh, a, 0, 0, 0);
            a = __builtin_amdgcn_mfma_f32_16x16x32_bf16(Eh, bl_, a, 0, 0, 0);
            a = __builtin_amdgcn_mfma_f32_16x16x32_bf16(El, bh, a, 0, 0, 0);
            float bev = bemb[l15 + 16 * nt];
#pragma unroll
            for (int i = 0; i < 4; i++) {
                float hv = a[i] + bev;
                h[(n0 + g * 4 + i) * 64 + l15 + 16 * nt] = hv;
                sh[wv][g * 4 + i][l15 + 16 * nt] = hv;
            }
        }
    }
    // x init (padded)
    {
        int nd = lane >> 2, cc = lane & 3;
        xp[(n0 + nd) * 4 + cc] = (cc < 3) ? x_in[(n0 + nd) * 3 + cc] : 0.f;
        if (cc < 3) dxb[(n0 + nd) * 3 + cc] = 0.f;
    }
    asm volatile("s_waitcnt lgkmcnt(0)" ::: "memory");   // wave-local LDS exchange

    // ---- A-frags for P/Q from sh (row l15, k = kh*32+g*8+b)
    v8bf Ah[2], Al[2];
#pragma unroll
    for (int kh = 0; kh < 2; kh++) {
        float v[8];
        *reinterpret_cast<float4*>(&v[0]) = *reinterpret_cast<const float4*>(&sh[wv][l15][kh * 32 + g * 8]);
        *reinterpret_cast<float4*>(&v[4]) = *reinterpret_cast<const float4*>(&sh[wv][l15][kh * 32 + g * 8 + 4]);
#pragma unroll
        for (int b = 0; b < 8; b++) {
            bf16 hi = (bf16)v[b];
            Ah[kh][b] = hi; Al[kh][b] = (bf16)(v[b] - (float)hi);
        }
    }

    const v8bf* Bh = reinterpret_cast<const v8bf*>(We1h);
    const v8bf* Bl = reinterpret_cast<const v8bf*>(We1l);

    float be1v[4];
#pragma unroll
    for (int nt = 0; nt < 4; nt++) be1v[nt] = be1[l15 + 16 * nt];

#pragma unroll
    for (int nt = 0; nt < 4; nt++) {
        v4f ap = {0.f,0.f,0.f,0.f}, aq = {0.f,0.f,0.f,0.f};
#pragma unroll
        for (int kh = 0; kh < 2; kh++) {
            int fiP = (kh * 4 + g) * 64 + l15 + 16 * nt;
            int fiQ = ((kh + 2) * 4 + g) * 64 + l15 + 16 * nt;
            v8bf bph = Bh[fiP], bpl = Bl[fiP];
            v8bf bqh = Bh[fiQ], bql = Bl[fiQ];
            ap = __builtin_amdgcn_mfma_f32_16x16x32_bf16(Ah[kh], bph, ap, 0, 0, 0);
            ap = __builtin_amdgcn_mfma_f32_16x16x32_bf16(Ah[kh], bpl, ap, 0, 0, 0);
            ap = __builtin_amdgcn_mfma_f32_16x16x32_bf16(Al[kh], bph, ap, 0, 0, 0);
            aq = __builtin_amdgcn_mfma_f32_16x16x32_bf16(Ah[kh], bqh, aq, 0, 0, 0);
            aq = __builtin_amdgcn_mfma_f32_16x16x32_bf16(Ah[kh], bql, aq, 0, 0, 0);
            aq = __builtin_amdgcn_mfma_f32_16x16x32_bf16(Al[kh], bqh, aq, 0, 0, 0);
        }
#pragma unroll
        for (int i = 0; i < 4; i++) {
            int ro = (n0 + g * 4 + i) * 64 + l15 + 16 * nt;
            P[ro] = ap[i] + be1v[nt];
            Q[ro] = aq[i];
            agg[ro] = 0.f;
        }
    }
}

// ---------------------------------------------------------------- edge chunk compute
__device__ __forceinline__ void edge_compute(
    int n, int ct, int sg,
    const float4& xn, const float4& xs,
    const float4* pw, const float4* qv4,
    const v8bf* __restrict__ BHf, const v8bf* __restrict__ BLf,
    const float (&wdv)[2][8], const float (&be2v)[4], const float (&wxv)[4],
    int g, int l15, int lane,
    float* __restrict__ agg, float* __restrict__ dxb)
{
    float rx = xs.x - xn.x, ry = xs.y - xn.y, rz = xs.z - xn.z;
    float d2 = rx * rx + ry * ry + rz * rz;
    const float* pv = reinterpret_cast<const float*>(pw);
    const float* qv = reinterpret_cast<const float*>(qv4);

    v8bf Ah[2], Al[2];
#pragma unroll
    for (int kh = 0; kh < 2; kh++) {
#pragma unroll
        for (int b = 0; b < 8; b++) {
            float m1 = silu_f(pv[kh * 8 + b] + qv[kh * 8 + b] + d2 * wdv[kh][b]);
            bf16 hi = (bf16)m1;
            Ah[kh][b] = hi;
            Al[kh][b] = (bf16)(m1 - (float)hi);
        }
    }

    v4f acc[4];
#pragma unroll
    for (int nt = 0; nt < 4; nt++) {
        v4f a = {0.f, 0.f, 0.f, 0.f};
#pragma unroll
        for (int kh = 0; kh < 2; kh++) {
            int fi = (kh * 4 + g) * 64 + l15 + 16 * nt;
            v8bf bh = BHf[fi], bl = BLf[fi];
            a = __builtin_amdgcn_mfma_f32_16x16x32_bf16(Ah[kh], bh, a, 0, 0, 0);
            a = __builtin_amdgcn_mfma_f32_16x16x32_bf16(Ah[kh], bl, a, 0, 0, 0);
            a = __builtin_amdgcn_mfma_f32_16x16x32_bf16(Al[kh], bh, a, 0, 0, 0);
        }
        acc[nt] = a;
    }

    float aggv[4] = {0.f, 0.f, 0.f, 0.f};
    float dxx = 0.f, dxy = 0.f, dxz = 0.f;
#pragma unroll
    for (int i = 0; i < 4; i++) {
        bool valid = (g * 4 + i) < ct;
        float m0 = silu_f(acc[0][i] + be2v[0]); m0 = valid ? m0 : 0.f;
        float m1 = silu_f(acc[1][i] + be2v[1]); m1 = valid ? m1 : 0.f;
        float m2 = silu_f(acc[2][i] + be2v[2]); m2 = valid ? m2 : 0.f;
        float m3 = silu_f(acc[3][i] + be2v[3]); m3 = valid ? m3 : 0.f;
        aggv[0] += m0; aggv[1] += m1; aggv[2] += m2; aggv[3] += m3;
        float pd = m0 * wxv[0] + m1 * wxv[1] + m2 * wxv[2] + m3 * wxv[3];
        pd += __shfl_xor(pd, 1); pd += __shfl_xor(pd, 2);
        pd += __shfl_xor(pd, 4); pd += __shfl_xor(pd, 8);
        float rxe = __shfl(rx, g * 4 + i);
        float rye = __shfl(ry, g * 4 + i);
        float rze = __shfl(rz, g * 4 + i);
        if (l15 == 0) { dxx += rxe * pd; dxy += rye * pd; dxz += rze * pd; }
    }

#pragma unroll
    for (int nt = 0; nt < 4; nt++) {
        aggv[nt] += __shfl_xor(aggv[nt], 16);
        aggv[nt] += __shfl_xor(aggv[nt], 32);
    }
    if (lane < 16) {
        if (sg) {
#pragma unroll
            for (int nt = 0; nt < 4; nt++) agg[n * 64 + l15 + 16 * nt] = aggv[nt];
        } else {
#pragma unroll
            for (int nt = 0; nt < 4; nt++) unsafeAtomicAdd(&agg[n * 64 + l15 + 16 * nt], aggv[nt]);
        }
    }
    dxx += __shfl_xor(dxx, 16); dxx += __shfl_xor(dxx, 32);
    dxy += __shfl_xor(dxy, 16); dxy += __shfl_xor(dxy, 32);
    dxz += __shfl_xor(dxz, 16); dxz += __shfl_xor(dxz, 32);
    if (lane == 0) {
        if (sg) {
            dxb[n * 3 + 0] = dxx; dxb[n * 3 + 1] = dxy; dxb[n * 3 + 2] = dxz;
        } else {
            unsafeAtomicAdd(&dxb[n * 3 + 0], dxx);
            unsafeAtomicAdd(&dxb[n * 3 + 1], dxy);
            unsafeAtomicAdd(&dxb[n * 3 + 2], dxz);
        }
    }
}

// ---------------------------------------------------------------- edge kernel: pipelined grid-stride
// min 5 waves/EU -> VGPR cap 102 (was 108): +1 resident wave/SIMD to fill issue bubbles
__global__ __launch_bounds__(256, 5) void k_edge_pipe(
    const int* __restrict__ srcp, const int2* __restrict__ cpair, const int* __restrict__ ncptr,
    const float* __restrict__ xp,
    const float* __restrict__ P, const float* __restrict__ Q,
    const float* __restrict__ Wd,
    const bf16* __restrict__ We2h, const bf16* __restrict__ We2l,
    const float* __restrict__ be2, const float* __restrict__ Wx,
    float* __restrict__ agg, float* __restrict__ dxb)
{
    const int wv = threadIdx.x >> 6, lane = threadIdx.x & 63;
    const int g = lane >> 4, l15 = lane & 15;
    const int Wstride = EBLK * 4;
    const int NC = *ncptr;
    int c0 = blockIdx.x * 4 + wv;
    if (c0 >= NC) return;

    const float4* xp4 = reinterpret_cast<const float4*>(xp);
    const float4* Pf4 = reinterpret_cast<const float4*>(P);
    const float4* Qf4 = reinterpret_cast<const float4*>(Q);
    const v8bf* BHf = reinterpret_cast<const v8bf*>(We2h);
    const v8bf* BLf = reinterpret_cast<const v8bf*>(We2l);

    float wdv[2][8];
    UNPACK8(wdv[0], Wd + g * 8);
    UNPACK8(wdv[1], Wd + 32 + g * 8);
    float be2v[4], wxv[4];
#pragma unroll
    for (int nt = 0; nt < 4; nt++) { be2v[nt] = be2[l15 + 16 * nt]; wxv[nt] = Wx[l15 + 16 * nt]; }

    // ---- pipeline prologue (3-deep: payload@+1, src/xn@+2, meta@+3)
    int c1 = c0 + Wstride, c2 = c1 + Wstride, c3 = c2 + Wstride;
    int2 m0 = cpair[c0];
    int2 m1 = cpair[min(c1, NC - 1)];
    int2 m2 = cpair[min(c2, NC - 1)];
    int n0 = m0.x, eb0 = m0.y & 0xFFFFF, ct0 = (m0.y >> 20) & 31, sg0 = (m0.y >> 25) & 1;
    int n1 = m1.x, eb1 = m1.y & 0xFFFFF, ct1 = (m1.y >> 20) & 31, sg1 = (m1.y >> 25) & 1;
    int s0 = srcp[eb0 + min(l15, ct0 - 1)];
    int s1 = srcp[eb1 + min(l15, ct1 - 1)];
    float4 xn0 = xp4[n0], xn1 = xp4[n1];
    float4 xs0 = xp4[s0];
    float4 pw0[4], qv0[4];
    pw0[0] = Pf4[s0 * 16 + g * 2];     pw0[1] = Pf4[s0 * 16 + g * 2 + 1];
    pw0[2] = Pf4[s0 * 16 + 8 + g * 2]; pw0[3] = Pf4[s0 * 16 + 8 + g * 2 + 1];
    qv0[0] = Qf4[n0 * 16 + g * 2];     qv0[1] = Qf4[n0 * 16 + g * 2 + 1];
    qv0[2] = Qf4[n0 * 16 + 8 + g * 2]; qv0[3] = Qf4[n0 * 16 + 8 + g * 2 + 1];

    while (true) {
        float4 xs1 = xp4[s1];
        float4 pw1[4], qv1[4];
        pw1[0] = Pf4[s1 * 16 + g * 2];     pw1[1] = Pf4[s1 * 16 + g * 2 + 1];
        pw1[2] = Pf4[s1 * 16 + 8 + g * 2]; pw1[3] = Pf4[s1 * 16 + 8 + g * 2 + 1];
        qv1[0] = Qf4[n1 * 16 + g * 2];     qv1[1] = Qf4[n1 * 16 + g * 2 + 1];
        qv1[2] = Qf4[n1 * 16 + 8 + g * 2]; qv1[3] = Qf4[n1 * 16 + 8 + g * 2 + 1];
        int n2 = m2.x, eb2 = m2.y & 0xFFFFF, ct2 = (m2.y >> 20) & 31, sg2 = (m2.y >> 25) & 1;
        int s2 = srcp[eb2 + min(l15, ct2 - 1)];
        float4 xn2 = xp4[n2];
        int2 m3 = cpair[min(c3, NC - 1)];

        edge_compute(n0, ct0, sg0, xn0, xs0, pw0, qv0,
                     BHf, BLf, wdv, be2v, wxv, g, l15, lane, agg, dxb);

        c0 = c1; c1 = c2; c2 = c3; c3 += Wstride;
        n0 = n1; ct0 = ct1; sg0 = sg1; xn0 = xn1; xs0 = xs1;
#pragma unroll
        for (int j = 0; j < 4; j++) { pw0[j] = pw1[j]; qv0[j] = qv1[j]; }
        n1 = n2; ct1 = ct2; sg1 = sg2; s1 = s2; xn1 = xn2;
        m2 = m3;
        if (c0 >= NC) break;
    }
}

// ---------------------------------------------------------------- node update (MFMA, split-bf16)
// optional fusions: do_lat (latent), do_pq (next layer P/Q), do_out (output head, L3)
__global__ __launch_bounds__(256) void k_node_mfma(
    float* __restrict__ h, float* __restrict__ xp,
    float* __restrict__ agg, const float* __restrict__ dxb,
    const bf16* __restrict__ Wn1h, const bf16* __restrict__ Wn1l, const float* __restrict__ bn1,
    const bf16* __restrict__ Wn2h, const bf16* __restrict__ Wn2l, const float* __restrict__ bn2,
    int do_pq,
    const bf16* __restrict__ We1nh, const bf16* __restrict__ We1nl, const float* __restrict__ be1n,
    float* __restrict__ P, float* __restrict__ Q, float* __restrict__ dxbz,
    int do_lat,
    const bf16* __restrict__ Wlh, const bf16* __restrict__ Wll, const float* __restrict__ bl,
    const bf16* __restrict__ Wuh, const bf16* __restrict__ Wul, const float* __restrict__ bu,
    int do_out,
    const bf16* __restrict__ Woh, const bf16* __restrict__ Wol, const float* __restrict__ bo,
    float* __restrict__ out)
{
    __shared__ float sh[4][16][68];
    __shared__ float su[4][16][68];

    const int wv = threadIdx.x >> 6, lane = threadIdx.x & 63;
    const int g = lane >> 4, l15 = lane & 15;
    const int n0 = (blockIdx.x * 4 + wv) * 16;
    if (n0 >= NN) return;                      // no block barriers below -> safe

    const int nrow = n0 + l15;

    v8bf Ah[4], Al[4];
#pragma unroll
    for (int kh = 0; kh < 2; kh++) {
        float v[8];
        UNPACK8(v, h + nrow * 64 + kh * 32 + g * 8);
        *reinterpret_cast<float4*>(&sh[wv][l15][kh * 32 + g * 8])     = *reinterpret_cast<const float4*>(&v[0]);
        *reinterpret_cast<float4*>(&sh[wv][l15][kh * 32 + g * 8 + 4]) = *reinterpret_cast<const float4*>(&v[4]);
#pragma unroll
        for (int b = 0; b < 8; b++) {
            bf16 hi = (bf16)v[b];
            Ah[kh][b] = hi; Al[kh][b] = (bf16)(v[b] - (float)hi);
        }
    }
#pragma unroll
    for (int kh = 0; kh < 2; kh++) {
        float v[8];
        UNPACK8(v, agg + nrow * 64 + kh * 32 + g * 8);
#pragma unroll
        for (int b = 0; b < 8; b++) {
            bf16 hi = (bf16)v[b];
            Ah[2 + kh][b] = hi; Al[2 + kh][b] = (bf16)(v[b] - (float)hi);
        }
    }

    const v8bf* B1h = reinterpret_cast<const v8bf*>(Wn1h);
    const v8bf* B1l = reinterpret_cast<const v8bf*>(Wn1l);
    const v8bf* B2h = reinterpret_cast<const v8bf*>(Wn2h);
    const v8bf* B2l = reinterpret_cast<const v8bf*>(Wn2l);

    float bn1v[4];
#pragma unroll
    for (int nt = 0; nt < 4; nt++) bn1v[nt] = bn1[l15 + 16 * nt];
#pragma unroll
    for (int nt = 0; nt < 4; nt++) {
        v4f a = {0.f, 0.f, 0.f, 0.f};
#pragma unroll
        for (int kh = 0; kh < 4; kh++) {
            int fi = (kh * 4 + g) * 64 + l15 + 16 * nt;
            v8bf bh = B1h[fi], bl_ = B1l[fi];
            a = __builtin_amdgcn_mfma_f32_16x16x32_bf16(Ah[kh], bh, a, 0, 0, 0);
            a = __builtin_amdgcn_mfma_f32_16x16x32_bf16(Ah[kh], bl_, a, 0, 0, 0);
            a = __builtin_amdgcn_mfma_f32_16x16x32_bf16(Al[kh], bh, a, 0, 0, 0);
        }
#pragma unroll
        for (int i = 0; i < 4; i++)
            su[wv][g * 4 + i][l15 + 16 * nt] = silu_f(a[i] + bn1v[nt]);
    }
    asm volatile("s_waitcnt lgkmcnt(0)" ::: "memory");

    v8bf Uh[2], Ul[2];
#pragma unroll
    for (int kh = 0; kh < 2; kh++) {
        float v[8];
        *reinterpret_cast<float4*>(&v[0]) = *reinterpret_cast<const float4*>(&su[wv][l15][kh * 32 + g * 8]);
        *reinterpret_cast<float4*>(&v[4]) = *reinterpret_cast<const float4*>(&su[wv][l15][kh * 32 + g * 8 + 4]);
#pragma unroll
        for (int b = 0; b < 8; b++) {
            bf16 hi = (bf16)v[b];
            Uh[kh][b] = hi; Ul[kh][b] = (bf16)(v[b] - (float)hi);
        }
    }

    float bn2v[4];
#pragma unroll
    for (int nt = 0; nt < 4; nt++) bn2v[nt] = bn2[l15 + 16 * nt];
#pragma unroll
    for (int nt = 0; nt < 4; nt++) {
        v4f a = {0.f, 0.f, 0.f, 0.f};
#pragma unroll
        for (int kh = 0; kh < 2; kh++) {
            int fi = (kh * 4 + g) * 64 + l15 + 16 * nt;
            v8bf bh = B2h[fi], bl_ = B2l[fi];
            a = __builtin_amdgcn_mfma_f32_16x16x32_bf16(Uh[kh], bh, a, 0, 0, 0);
            a = __builtin_amdgcn_mfma_f32_16x16x32_bf16(Uh[kh], bl_, a, 0, 0, 0);
            a = __builtin_amdgcn_mfma_f32_16x16x32_bf16(Ul[kh], bh, a, 0, 0, 0);
        }
#pragma unroll
        for (int i = 0; i < 4; i++) {
            float hout = sh[wv][g * 4 + i][l15 + 16 * nt] + a[i] + bn2v[nt];
            if (!do_lat && !do_out) h[(n0 + g * 4 + i) * 64 + l15 + 16 * nt] = hout;
            if (do_pq || do_lat || do_out) sh[wv][g * 4 + i][l15 + 16 * nt] = hout;
        }
    }

    {
        int nd = lane >> 2, cc = lane & 3;
        if (cc < 3) {
            float xnew = xp[(n0 + nd) * 4 + cc] + dxb[(n0 + nd) * 3 + cc] * (1.f / 16.f);
            if (do_out) {
                out[(n0 + nd) * 19 + 16 + cc] = xnew;
            } else {
                xp[(n0 + nd) * 4 + cc] = xnew;
                if (do_pq) dxbz[(n0 + nd) * 3 + cc] = 0.f;
            }
        }
    }

    if (do_lat) {
        asm volatile("s_waitcnt lgkmcnt(0)" ::: "memory");
        v8bf Hh[2], Hl[2];
#pragma unroll
        for (int kh = 0; kh < 2; kh++) {
            float v[8];
            *reinterpret_cast<float4*>(&v[0]) = *reinterpret_cast<const float4*>(&sh[wv][l15][kh * 32 + g * 8]);
            *reinterpret_cast<float4*>(&v[4]) = *reinterpret_cast<const float4*>(&sh[wv][l15][kh * 32 + g * 8 + 4]);
#pragma unroll
            for (int b = 0; b < 8; b++) {
                bf16 hi = (bf16)v[b];
                Hh[kh][b] = hi; Hl[kh][b] = (bf16)(v[b] - (float)hi);
            }
        }
        const v8bf* BLh = reinterpret_cast<const v8bf*>(Wlh);
        const v8bf* BLl = reinterpret_cast<const v8bf*>(Wll);
#pragma unroll
        for (int nt = 0; nt < 2; nt++) {
            v4f a = {0.f, 0.f, 0.f, 0.f};
#pragma unroll
            for (int kh = 0; kh < 2; kh++) {
                int fi = (kh * 4 + g) * 32 + l15 + 16 * nt;
                v8bf bh = BLh[fi], bl_ = BLl[fi];
                a = __builtin_amdgcn_mfma_f32_16x16x32_bf16(Hh[kh], bh, a, 0, 0, 0);
                a = __builtin_amdgcn_mfma_f32_16x16x32_bf16(Hh[kh], bl_, a, 0, 0, 0);
                a = __builtin_amdgcn_mfma_f32_16x16x32_bf16(Hl[kh], bh, a, 0, 0, 0);
            }
            float blv = bl[l15 + 16 * nt];
#pragma unroll
            for (int i = 0; i < 4; i++)
                su[wv][g * 4 + i][l15 + 16 * nt] = a[i] + blv;
        }
        asm volatile("s_waitcnt lgkmcnt(0)" ::: "memory");

        v8bf Zh, Zl;
        {
            float v[8];
            *reinterpret_cast<float4*>(&v[0]) = *reinterpret_cast<const float4*>(&su[wv][l15][g * 8]);
            *reinterpret_cast<float4*>(&v[4]) = *reinterpret_cast<const float4*>(&su[wv][l15][g * 8 + 4]);
#pragma unroll
            for (int b = 0; b < 8; b++) {
                bf16 hi = (bf16)v[b];
                Zh[b] = hi; Zl[b] = (bf16)(v[b] - (float)hi);
            }
        }
        const v8bf* BUh = reinterpret_cast<const v8bf*>(Wuh);
        const v8bf* BUl = reinterpret_cast<const v8bf*>(Wul);
#pragma unroll
        for (int nt = 0; nt < 4; nt++) {
            v4f a = {0.f, 0.f, 0.f, 0.f};
            int fi = g * 64 + l15 + 16 * nt;
            v8bf bh = BUh[fi], bl_ = BUl[fi];
            a = __builtin_amdgcn_mfma_f32_16x16x32_bf16(Zh, bh, a, 0, 0, 0);
            a = __builtin_amdgcn_mfma_f32_16x16x32_bf16(Zh, bl_, a, 0, 0, 0);
            a = __builtin_amdgcn_mfma_f32_16x16x32_bf16(Zl, bh, a, 0, 0, 0);
            float buv = bu[l15 + 16 * nt];
#pragma unroll
            for (int i = 0; i < 4; i++) {
                float hout = a[i] + buv;
                h[(n0 + g * 4 + i) * 64 + l15 + 16 * nt] = hout;
                sh[wv][g * 4 + i][l15 + 16 * nt] = hout;
            }
        }
    }

    if (do_pq) {
        asm volatile("s_waitcnt lgkmcnt(0)" ::: "memory");
        v8bf Hh[2], Hl[2];
#pragma unroll
        for (int kh = 0; kh < 2; kh++) {
            float v[8];
            *reinterpret_cast<float4*>(&v[0]) = *reinterpret_cast<const float4*>(&sh[wv][l15][kh * 32 + g * 8]);
            *reinterpret_cast<float4*>(&v[4]) = *reinterpret_cast<const float4*>(&sh[wv][l15][kh * 32 + g * 8 + 4]);
#pragma unroll
            for (int b = 0; b < 8; b++) {
                bf16 hi = (bf16)v[b];
                Hh[kh][b] = hi; Hl[kh][b] = (bf16)(v[b] - (float)hi);
            }
        }
        const v8bf* Bh = reinterpret_cast<const v8bf*>(We1nh);
        const v8bf* Bl = reinterpret_cast<const v8bf*>(We1nl);
        float be1v[4];
#pragma unroll
        for (int nt = 0; nt < 4; nt++) be1v[nt] = be1n[l15 + 16 * nt];
#pragma unroll
        for (int nt = 0; nt < 4; nt++) {
            v4f ap = {0.f,0.f,0.f,0.f}, aq = {0.f,0.f,0.f,0.f};
#pragma unroll
            for (int kh = 0; kh < 2; kh++) {
                int fiP = (kh * 4 + g) * 64 + l15 + 16 * nt;
                int fiQ = ((kh + 2) * 4 + g) * 64 + l15 + 16 * nt;
                v8bf bph = Bh[fiP], bpl = Bl[fiP];
                v8bf bqh = Bh[fiQ], bql = Bl[fiQ];
                ap = __builtin_amdgcn_mfma_f32_16x16x32_bf16(Hh[kh], bph, ap, 0, 0, 0);
                ap = __builtin_amdgcn_mfma_f32_16x16x32_bf16(Hh[kh], bpl, ap, 0, 0, 0);
                ap = __builtin_amdgcn_mfma_f32_16x16x32_bf16(Hl[kh], bph, ap, 0, 0, 0);
                aq = __builtin_amdgcn_mfma_f32_16x16x32_bf16(Hh[kh], bqh, aq, 0, 0, 0);
                aq = __builtin_amdgcn_mfma_f32_16x16x32_bf16(Hh[kh], bql, aq, 0, 0, 0);
                aq = __builtin_amdgcn_mfma_f32_16x16x32_bf16(Hl[kh], bqh, aq, 0, 0, 0);
            }
#pragma unroll
            for (int i = 0; i < 4; i++) {
                int ro = (n0 + g * 4 + i) * 64 + l15 + 16 * nt;
                P[ro] = ap[i] + be1v[nt];
                Q[ro] = aq[i];
                agg[ro] = 0.f;
            }
        }
    }

    if (do_out) {
        asm volatile("s_waitcnt lgkmcnt(0)" ::: "memory");
        v8bf Hh[2], Hl[2];
#pragma unroll
        for (int kh = 0; kh < 2; kh++) {
            float v[8];
            *reinterpret_cast<float4*>(&v[0]) = *reinterpret_cast<const float4*>(&sh[wv][l15][kh * 32 + g * 8]);
            *reinterpret_cast<float4*>(&v[4]) = *reinterpret_cast<const float4*>(&sh[wv][l15][kh * 32 + g * 8 + 4]);
#pragma unroll
            for (int b = 0; b < 8; b++) {
                bf16 hi = (bf16)v[b];
                Hh[kh][b] = hi; Hl[kh][b] = (bf16)(v[b] - (float)hi);
            }
        }
        const v8bf* BOh = reinterpret_cast<const v8bf*>(Woh);
        const v8bf* BOl = reinterpret_cast<const v8bf*>(Wol);
        float bov = bo[l15];
        v4f a = {0.f, 0.f, 0.f, 0.f};
#pragma unroll
        for (int kh = 0; kh < 2; kh++) {
            int fi = (kh * 4 + g) * 16 + l15;
            v8bf bh = BOh[fi], bl_ = BOl[fi];
            a = __builtin_amdgcn_mfma_f32_16x16x32_bf16(Hh[kh], bh, a, 0, 0, 0);
            a = __builtin_amdgcn_mfma_f32_16x16x32_bf16(Hh[kh], bl_, a, 0, 0, 0);
            a = __builtin_amdgcn_mfma_f32_16x16x32_bf16(Hl[kh], bh, a, 0, 0, 0);
        }
#pragma unroll
        for (int i = 0; i < 4; i++)
            out[(n0 + g * 4 + i) * 19 + l15] = a[i] + bov;
    }
}

extern "C" void kernel_launch(void* const* d_in, const int* in_sizes, int n_in,
                              void* d_out, int out_size, void* d_ws, size_t ws_size,
                              hipStream_t stream)
{
    const float* h_in  = (const float*)d_in[0];
    const float* x_in  = (const float*)d_in[1];
    const int*   ei    = (const int*)d_in[2];
    const float* W_emb = (const float*)d_in[3];
    const float* b_emb = (const float*)d_in[4];
    const float* W_lat = (const float*)d_in[5];
    const float* b_lat = (const float*)d_in[6];
    const float* W_up  = (const float*)d_in[7];
    const float* b_up  = (const float*)d_in[8];
    const float* W_out = (const float*)d_in[9];
    const float* b_out = (const float*)d_in[10];
    const float* encp[9]; const float* decp[9];
    for (int i = 0; i < 9; i++) { encp[i] = (const float*)d_in[11 + i]; decp[i] = (const float*)d_in[20 + i]; }

    const int* src = ei;
    const int* dst = ei + NE;

    // workspace layout
    float* ws  = (float*)d_ws;
    float* h   = ws;                       // NN*64
    float* xp  = h + NN * 64;              // NN*4
    float* P   = xp + NN * 4;              // NN*64
    float* Q   = P + NN * 64;              // NN*64
    float* agg = Q + NN * 64;              // NN*64
    float* dxb = agg + NN * 64;            // NN*3
    int* off   = (int*)(dxb + NN * 3);     // NN+1
    int* cur   = off + (NN + 1);           // NN+1
    int* bsum  = cur + (NN + 1);           // 2*SCB
    int* bbase = bsum + 2 * SCB;           // 2*SCB
    int* srcp  = bbase + 2 * SCB;          // NE
    int* ncptr = srcp + NE;                // 1 (+1 pad for int2 align)
    int2* cpair = (int2*)(ncptr + 2);      // MAXC
    bf16* We1h = (bf16*)(cpair + MAXC);    // 4*8192
    bf16* We1l = We1h + 4 * 8192;
    bf16* We2h = We1l + 4 * 8192;          // 4*4096
    bf16* We2l = We2h + 4 * 4096;
    bf16* Wn1h = We2l + 4 * 4096;          // 4*8192
    bf16* Wn1l = Wn1h + 4 * 8192;
    bf16* Wn2h = Wn1l + 4 * 8192;          // 4*4096
    bf16* Wn2l = Wn2h + 4 * 4096;
    bf16* Wlh  = Wn2l + 4 * 4096;          // 2048
    bf16* Wll  = Wlh + 2048;
    bf16* Wuh  = Wll + 2048;               // 2048
    bf16* Wul  = Wuh + 2048;
    bf16* Wembh = Wul + 2048;              // 2048 (K padded to 32)
    bf16* Wembl = Wembh + 2048;
    bf16* Wouth = Wembl + 2048;            // 1024
    bf16* Woutl = Wouth + 1024;

    // ---- one-time: CSR by dst, chunk meta (fused), weight prep
    hipMemsetAsync(cur, 0, (NN + 1) * sizeof(int), stream);
    k_hist<<<NE / 256, 256, 0, stream>>>(dst, cur);
    k_blocksum<<<SCB, 256, 0, stream>>>(cur, bsum);
    k_scanbase<<<1, 256, 0, stream>>>(bsum, bbase, ncptr);
    k_applyscan<<<SCB, 256, 0, stream>>>(cur, bbase, off, cur, cpair);
    k_scatter<<<NE / 256, 256, 0, stream>>>(dst, src, cur, srcp);
    k_prep_all<<<412, 256, 0, stream>>>(encp[0], decp[0], encp[2], decp[2],
                                        encp[5], decp[5], encp[7], decp[7],
                                        W_lat, W_up, W_emb, W_out,
                                        We1h, We1l, We2h, We2l, Wn1h, Wn1l, Wn2h, Wn2l,
                                        Wlh, Wll, Wuh, Wul, Wembh, Wembl, Wouth, Woutl);

    const int NODE_GRID = (NN / 16 + 3) / 4;

    // L0: embed + P/Q fused
    k_pq_mfma<<<NODE_GRID, 256, 0, stream>>>(h_in, x_in, Wembh, Wembl, b_emb, h, xp,
                                             We1h, We1l, encp[1], P, Q, agg, dxb);

    for (int L = 0; L < 4; ++L) {
        const float** pp = (L < 2) ? encp : decp;
        int li = (L < 2) ? L : L - 2;
        const float* We1 = pp[0] + li * 129 * 64;
        const float* be2 = pp[3] + li * 64;
        const float* Wx  = pp[4] + li * 64;
        const float* bn1 = pp[6] + li * 64;
        const float* bn2 = pp[8] + li * 64;

        k_edge_pipe<<<EBLK, 256, 0, stream>>>(srcp, cpair, ncptr,
                                              xp, P, Q, We1 + 128 * 64,
                                              We2h + L * 4096, We2l + L * 4096,
                                              be2, Wx, agg, dxb);

        int do_pq = (L < 3) ? 1 : 0;
        int do_lat = (L == 1) ? 1 : 0;
        int do_out = (L == 3) ? 1 : 0;
        int Ln = L + 1;   // packed order enc0,enc1,dec0,dec1
        const float* be1n = bn1;
        if (do_pq) be1n = (Ln < 2 ? encp[1] : decp[1]) + ((Ln < 2 ? Ln : Ln - 2)) * 64;

        k_node_mfma<<<NODE_GRID, 256, 0, stream>>>(h, xp, agg, dxb,
                                                   Wn1h + L * 8192, Wn1l + L * 8192, bn1,
                                                   Wn2h + L * 4096, Wn2l + L * 4096, bn2,
                                                   do_pq,
                                                   We1h + (do_pq ? Ln : 0) * 8192,
                                                   We1l + (do_pq ? Ln : 0) * 8192, be1n,
                                                   P, Q, dxb,
                                                   do_lat, Wlh, Wll, b_lat, Wuh, Wul, b_up,
                                                   do_out, Wouth, Woutl, b_out, (float*)d_out);
    }
}

// Round 15
// 554.160 us; speedup vs baseline: 2.6563x; 2.6563x over previous
//
#include <hip/hip_runtime.h>

#define NN 50000
#define NE 800000
#define MAXC 100000
#define EBLK 1024     // 4 blocks/CU resident; T ~= 16 amortizes pipeline fill
#define SCB ((NN + 255) / 256)   // scan blocks = 196

__device__ __forceinline__ float silu_f(float v) {
    return v * __builtin_amdgcn_rcpf(1.f + __expf(-v));
}

typedef __bf16 bf16;
typedef bf16 v8bf __attribute__((ext_vector_type(8)));
typedef float v4f __attribute__((ext_vector_type(4)));

#define UNPACK8(dstv, ptr) { \
    float4 _a = reinterpret_cast<const float4*>(ptr)[0]; \
    float4 _b = reinterpret_cast<const float4*>(ptr)[1]; \
    dstv[0]=_a.x; dstv[1]=_a.y; dstv[2]=_a.z; dstv[3]=_a.w; \
    dstv[4]=_b.x; dstv[5]=_b.y; dstv[6]=_b.z; dstv[7]=_b.w; }

// ---------------------------------------------------------------- fused weight prep (8 tensors)
// hi/lo bf16 split in MFMA B-fragment order: dst ((kh*4+g)*Ncol+col)*8+b, k=kh*32+g*8+b
__global__ __launch_bounds__(256) void k_prep_all(
    const float* __restrict__ eW1, const float* __restrict__ dW1,
    const float* __restrict__ eW2, const float* __restrict__ dW2,
    const float* __restrict__ eN1, const float* __restrict__ dN1,
    const float* __restrict__ eN2, const float* __restrict__ dN2,
    const float* __restrict__ Wlat, const float* __restrict__ Wup,
    const float* __restrict__ Wemb, const float* __restrict__ Wout,
    bf16* __restrict__ We1h, bf16* __restrict__ We1l,
    bf16* __restrict__ We2h, bf16* __restrict__ We2l,
    bf16* __restrict__ Wn1h, bf16* __restrict__ Wn1l,
    bf16* __restrict__ Wn2h, bf16* __restrict__ Wn2l,
    bf16* __restrict__ Wlh,  bf16* __restrict__ Wll,
    bf16* __restrict__ Wuh,  bf16* __restrict__ Wul,
    bf16* __restrict__ Wembh, bf16* __restrict__ Wembl,
    bf16* __restrict__ Wouth, bf16* __restrict__ Woutl)
{
    int t = blockIdx.x * 256 + threadIdx.x;   // total 105472 = 412 blocks
    float w; int di; bf16 *Wh, *Wl;
    if (t < 98304) {
        const float *encW, *decW; int K, stride; int r;
        if (t < 32768)      { r = t;         encW = eW1; decW = dW1; K = 128; stride = 129 * 64; Wh = We1h; Wl = We1l; }
        else if (t < 49152) { r = t - 32768; encW = eW2; decW = dW2; K = 64;  stride = 64 * 64;  Wh = We2h; Wl = We2l; }
        else if (t < 81920) { r = t - 49152; encW = eN1; decW = dN1; K = 128; stride = 128 * 64; Wh = Wn1h; Wl = Wn1l; }
        else                { r = t - 81920; encW = eN2; decW = dN2; K = 64;  stride = 64 * 64;  Wh = Wn2h; Wl = Wn2l; }
        int per = K * 64;
        int li = r / per, rr = r - li * per;
        int k = rr >> 6, col = rr & 63;
        const float* Wsrc = (li < 2 ? encW : decW) + (li & 1) * stride;
        w = Wsrc[k * 64 + col];
        int kh = k >> 5, gg = (k >> 3) & 3, b = k & 7;
        di = li * per + (((kh * 4 + gg) * 64 + col) * 8 + b);
    } else if (t < 100352) {
        int r = t - 98304;                    // Wlat: K=64, Ncol=32
        int k = r >> 5, col = r & 31;
        w = Wlat[k * 32 + col];
        int kh = k >> 5, gg = (k >> 3) & 3, b = k & 7;
        di = ((kh * 4 + gg) * 32 + col) * 8 + b;
        Wh = Wlh; Wl = Wll;
    } else if (t < 102400) {
        int r = t - 100352;                   // Wup: K=32, Ncol=64
        int k = r >> 6, col = r & 63;
        w = Wup[k * 64 + col];
        int gg = (k >> 3) & 3, b = k & 7;
        di = (gg * 64 + col) * 8 + b;
        Wh = Wuh; Wl = Wul;
    } else if (t < 104448) {
        int r = t - 102400;                   // Wemb: K=16 (padded to 32), Ncol=64
        int gg = r >> 9, col = (r >> 3) & 63, b = r & 7;
        int k = gg * 8 + b;
        w = (k < 16) ? Wemb[k * 64 + col] : 0.f;
        di = r;                               // (gg*64+col)*8+b
        Wh = Wembh; Wl = Wembl;
    } else if (t < 105472) {
        int r = t - 104448;                   // Wout: K=64, Ncol=16
        int kh4g = r >> 7, col = (r >> 3) & 15, b = r & 7;
        int kh = kh4g >> 2, gg = kh4g & 3;
        int k = kh * 32 + gg * 8 + b;
        w = Wout[k * 16 + col];
        di = r;                               // ((kh*4+gg)*16+col)*8+b
        Wh = Wouth; Wl = Woutl;
    } else return;
    bf16 hi = (bf16)w;
    Wh[di] = hi; Wl[di] = (bf16)(w - (float)hi);
}

// ---------------------------------------------------------------- CSR build (by dst)
__global__ __launch_bounds__(256) void k_hist(const int* __restrict__ dst, int* __restrict__ cnt)
{
    int e = blockIdx.x * 256 + threadIdx.x;
    if (e < NE) atomicAdd(&cnt[dst[e]], 1);
}

__global__ __launch_bounds__(256) void k_blocksum(
    const int* __restrict__ cnt, int* __restrict__ bsum)
{
    int b = blockIdx.x, tid = threadIdx.x;
    int i = b * 256 + tid;
    int deg = (i < NN) ? cnt[i] : 0;
    int chk = (deg + 15) >> 4;
#pragma unroll
    for (int d = 1; d < 64; d <<= 1) { deg += __shfl_xor(deg, d); chk += __shfl_xor(chk, d); }
    __shared__ int sd[4], sc[4];
    int wv = tid >> 6;
    if ((tid & 63) == 0) { sd[wv] = deg; sc[wv] = chk; }
    __syncthreads();
    if (tid == 0) {
        bsum[b] = sd[0] + sd[1] + sd[2] + sd[3];
        bsum[SCB + b] = sc[0] + sc[1] + sc[2] + sc[3];
    }
}

__global__ __launch_bounds__(256) void k_scanbase(
    const int* __restrict__ bsum, int* __restrict__ bbase, int* __restrict__ ncptr)
{
    __shared__ int s[256], s2[256];
    int tid = threadIdx.x;
    int v  = (tid < SCB) ? bsum[tid] : 0;
    int v2 = (tid < SCB) ? bsum[SCB + tid] : 0;
    s[tid] = v; s2[tid] = v2;
    __syncthreads();
    for (int d = 1; d < 256; d <<= 1) {
        int u  = (tid >= d) ? s[tid - d] : 0;
        int u2 = (tid >= d) ? s2[tid - d] : 0;
        __syncthreads();
        s[tid] += u; s2[tid] += u2;
        __syncthreads();
    }
    if (tid < SCB) {
        bbase[tid]       = s[tid] - v;
        bbase[SCB + tid] = s2[tid] - v2;
    }
    if (tid == 255) *ncptr = s2[SCB - 1];
}

// phase 3: per-block local scan + base apply -> off, cur; fused chunk-meta fill
__global__ __launch_bounds__(256) void k_applyscan(
    int* __restrict__ cnt, const int* __restrict__ bbase,
    int* __restrict__ off, int* __restrict__ cur, int2* __restrict__ cpair)
{
    int b = blockIdx.x, tid = threadIdx.x;
    int i = b * 256 + tid;
    int deg = (i < NN) ? cnt[i] : 0;
    int chk = (deg + 15) >> 4;
    __shared__ int s[256], s2[256];
    s[tid] = deg; s2[tid] = chk;
    __syncthreads();
    for (int d = 1; d < 256; d <<= 1) {
        int u  = (tid >= d) ? s[tid - d] : 0;
        int u2 = (tid >= d) ? s2[tid - d] : 0;
        __syncthreads();
        s[tid] += u; s2[tid] += u2;
        __syncthreads();
    }
    if (i < NN) {
        int o = bbase[b] + s[tid] - deg;
        off[i] = o; cur[i] = o;
        int co = bbase[SCB + b] + s2[tid] - chk;
        int e = o + deg;
        int single = (deg <= 16) ? (1 << 25) : 0;
        for (int eb = o; eb < e; eb += 16) {
            int c = min(e - eb, 16);
            cpair[co++] = make_int2(i, eb | (c << 20) | single);
        }
    }
    if (i == 0) off[NN] = NE;
}

__global__ __launch_bounds__(256) void k_scatter(
    const int* __restrict__ dst, const int* __restrict__ srcArr,
    int* __restrict__ cur, int* __restrict__ srcp)
{
    int e = blockIdx.x * 256 + threadIdx.x;
    if (e < NE) { int p = atomicAdd(&cur[dst[e]], 1); srcp[p] = srcArr[e]; }
}

// ------------------------------- L0: embed (MFMA, K=16 padded) + P/Q + zero agg/dxb + x init
__global__ __launch_bounds__(256) void k_pq_mfma(
    const float* __restrict__ h_in, const float* __restrict__ x_in,
    const bf16* __restrict__ Wembh, const bf16* __restrict__ Wembl, const float* __restrict__ bemb,
    float* __restrict__ h, float* __restrict__ xp,
    const bf16* __restrict__ We1h, const bf16* __restrict__ We1l,
    const float* __restrict__ be1,
    float* __restrict__ P, float* __restrict__ Q,
    float* __restrict__ agg, float* __restrict__ dxb)
{
    __shared__ float sh[4][16][68];
    const int wv = threadIdx.x >> 6, lane = threadIdx.x & 63;
    const int g = lane >> 4, l15 = lane & 15;
    const int n0 = (blockIdx.x * 4 + wv) * 16;
    if (n0 >= NN) return;
    const int nrow = n0 + l15;

    // ---- embed: h = h_in @ W_emb + b_emb (A-frag k = g*8+b, valid k<16 -> g<2)
    v8bf Eh, El;
    if (g < 2) {
        float ev[8];
        UNPACK8(ev, h_in + nrow * 16 + g * 8);
#pragma unroll
        for (int b = 0; b < 8; b++) {
            bf16 hi = (bf16)ev[b];
            Eh[b] = hi; El[b] = (bf16)(ev[b] - (float)hi);
        }
    } else {
#pragma unroll
        for (int b = 0; b < 8; b++) { Eh[b] = (bf16)0.f; El[b] = (bf16)0.f; }
    }
    {
        const v8bf* BEh = reinterpret_cast<const v8bf*>(Wembh);
        const v8bf* BEl = reinterpret_cast<const v8bf*>(Wembl);
#pragma unroll
        for (int nt = 0; nt < 4; nt++) {
            v4f a = {0.f, 0.f, 0.f, 0.f};
            int fi = g * 64 + l15 + 16 * nt;
            v8bf bh = BEh[fi], bl_ = BEl[fi];
            a = __builtin_amdgcn_mfma_f32_16x16x32_bf16(Eh, bh, a, 0, 0, 0);
            a = __builtin_amdgcn_mfma_f32_16x16x32_bf16(Eh, bl_, a, 0, 0, 0);
            a = __builtin_amdgcn_mfma_f32_16x16x32_bf16(El, bh, a, 0, 0, 0);
            float bev = bemb[l15 + 16 * nt];
#pragma unroll
            for (int i = 0; i < 4; i++) {
                float hv = a[i] + bev;
                h[(n0 + g * 4 + i) * 64 + l15 + 16 * nt] = hv;
                sh[wv][g * 4 + i][l15 + 16 * nt] = hv;
            }
        }
    }
    // x init (padded)
    {
        int nd = lane >> 2, cc = lane & 3;
        xp[(n0 + nd) * 4 + cc] = (cc < 3) ? x_in[(n0 + nd) * 3 + cc] : 0.f;
        if (cc < 3) dxb[(n0 + nd) * 3 + cc] = 0.f;
    }
    asm volatile("s_waitcnt lgkmcnt(0)" ::: "memory");   // wave-local LDS exchange

    // ---- A-frags for P/Q from sh (row l15, k = kh*32+g*8+b)
    v8bf Ah[2], Al[2];
#pragma unroll
    for (int kh = 0; kh < 2; kh++) {
        float v[8];
        *reinterpret_cast<float4*>(&v[0]) = *reinterpret_cast<const float4*>(&sh[wv][l15][kh * 32 + g * 8]);
        *reinterpret_cast<float4*>(&v[4]) = *reinterpret_cast<const float4*>(&sh[wv][l15][kh * 32 + g * 8 + 4]);
#pragma unroll
        for (int b = 0; b < 8; b++) {
            bf16 hi = (bf16)v[b];
            Ah[kh][b] = hi; Al[kh][b] = (bf16)(v[b] - (float)hi);
        }
    }

    const v8bf* Bh = reinterpret_cast<const v8bf*>(We1h);
    const v8bf* Bl = reinterpret_cast<const v8bf*>(We1l);

    float be1v[4];
#pragma unroll
    for (int nt = 0; nt < 4; nt++) be1v[nt] = be1[l15 + 16 * nt];

#pragma unroll
    for (int nt = 0; nt < 4; nt++) {
        v4f ap = {0.f,0.f,0.f,0.f}, aq = {0.f,0.f,0.f,0.f};
#pragma unroll
        for (int kh = 0; kh < 2; kh++) {
            int fiP = (kh * 4 + g) * 64 + l15 + 16 * nt;
            int fiQ = ((kh + 2) * 4 + g) * 64 + l15 + 16 * nt;
            v8bf bph = Bh[fiP], bpl = Bl[fiP];
            v8bf bqh = Bh[fiQ], bql = Bl[fiQ];
            ap = __builtin_amdgcn_mfma_f32_16x16x32_bf16(Ah[kh], bph, ap, 0, 0, 0);
            ap = __builtin_amdgcn_mfma_f32_16x16x32_bf16(Ah[kh], bpl, ap, 0, 0, 0);
            ap = __builtin_amdgcn_mfma_f32_16x16x32_bf16(Al[kh], bph, ap, 0, 0, 0);
            aq = __builtin_amdgcn_mfma_f32_16x16x32_bf16(Ah[kh], bqh, aq, 0, 0, 0);
            aq = __builtin_amdgcn_mfma_f32_16x16x32_bf16(Ah[kh], bql, aq, 0, 0, 0);
            aq = __builtin_amdgcn_mfma_f32_16x16x32_bf16(Al[kh], bqh, aq, 0, 0, 0);
        }
#pragma unroll
        for (int i = 0; i < 4; i++) {
            int ro = (n0 + g * 4 + i) * 64 + l15 + 16 * nt;
            P[ro] = ap[i] + be1v[nt];
            Q[ro] = aq[i];
            agg[ro] = 0.f;
        }
    }
}

// ---------------------------------------------------------------- edge chunk compute
__device__ __forceinline__ void edge_compute(
    int n, int ct, int sg,
    const float4& xn, const float4& xs,
    const float4* pw, const float4* qv4,
    const v8bf* __restrict__ BHf, const v8bf* __restrict__ BLf,
    const float (&wdv)[2][8], const float (&be2v)[4], const float (&wxv)[4],
    int g, int l15, int lane,
    float* __restrict__ agg, float* __restrict__ dxb)
{
    float rx = xs.x - xn.x, ry = xs.y - xn.y, rz = xs.z - xn.z;
    float d2 = rx * rx + ry * ry + rz * rz;
    const float* pv = reinterpret_cast<const float*>(pw);
    const float* qv = reinterpret_cast<const float*>(qv4);

    v8bf Ah[2], Al[2];
#pragma unroll
    for (int kh = 0; kh < 2; kh++) {
#pragma unroll
        for (int b = 0; b < 8; b++) {
            float m1 = silu_f(pv[kh * 8 + b] + qv[kh * 8 + b] + d2 * wdv[kh][b]);
            bf16 hi = (bf16)m1;
            Ah[kh][b] = hi;
            Al[kh][b] = (bf16)(m1 - (float)hi);
        }
    }

    v4f acc[4];
#pragma unroll
    for (int nt = 0; nt < 4; nt++) {
        v4f a = {0.f, 0.f, 0.f, 0.f};
#pragma unroll
        for (int kh = 0; kh < 2; kh++) {
            int fi = (kh * 4 + g) * 64 + l15 + 16 * nt;
            v8bf bh = BHf[fi], bl = BLf[fi];
            a = __builtin_amdgcn_mfma_f32_16x16x32_bf16(Ah[kh], bh, a, 0, 0, 0);
            a = __builtin_amdgcn_mfma_f32_16x16x32_bf16(Ah[kh], bl, a, 0, 0, 0);
            a = __builtin_amdgcn_mfma_f32_16x16x32_bf16(Al[kh], bh, a, 0, 0, 0);
        }
        acc[nt] = a;
    }

    float aggv[4] = {0.f, 0.f, 0.f, 0.f};
    float dxx = 0.f, dxy = 0.f, dxz = 0.f;
#pragma unroll
    for (int i = 0; i < 4; i++) {
        bool valid = (g * 4 + i) < ct;
        float m0 = silu_f(acc[0][i] + be2v[0]); m0 = valid ? m0 : 0.f;
        float m1 = silu_f(acc[1][i] + be2v[1]); m1 = valid ? m1 : 0.f;
        float m2 = silu_f(acc[2][i] + be2v[2]); m2 = valid ? m2 : 0.f;
        float m3 = silu_f(acc[3][i] + be2v[3]); m3 = valid ? m3 : 0.f;
        aggv[0] += m0; aggv[1] += m1; aggv[2] += m2; aggv[3] += m3;
        float pd = m0 * wxv[0] + m1 * wxv[1] + m2 * wxv[2] + m3 * wxv[3];
        pd += __shfl_xor(pd, 1); pd += __shfl_xor(pd, 2);
        pd += __shfl_xor(pd, 4); pd += __shfl_xor(pd, 8);
        float rxe = __shfl(rx, g * 4 + i);
        float rye = __shfl(ry, g * 4 + i);
        float rze = __shfl(rz, g * 4 + i);
        if (l15 == 0) { dxx += rxe * pd; dxy += rye * pd; dxz += rze * pd; }
    }

#pragma unroll
    for (int nt = 0; nt < 4; nt++) {
        aggv[nt] += __shfl_xor(aggv[nt], 16);
        aggv[nt] += __shfl_xor(aggv[nt], 32);
    }
    if (lane < 16) {
        if (sg) {
#pragma unroll
            for (int nt = 0; nt < 4; nt++) agg[n * 64 + l15 + 16 * nt] = aggv[nt];
        } else {
#pragma unroll
            for (int nt = 0; nt < 4; nt++) unsafeAtomicAdd(&agg[n * 64 + l15 + 16 * nt], aggv[nt]);
        }
    }
    dxx += __shfl_xor(dxx, 16); dxx += __shfl_xor(dxx, 32);
    dxy += __shfl_xor(dxy, 16); dxy += __shfl_xor(dxy, 32);
    dxz += __shfl_xor(dxz, 16); dxz += __shfl_xor(dxz, 32);
    if (lane == 0) {
        if (sg) {
            dxb[n * 3 + 0] = dxx; dxb[n * 3 + 1] = dxy; dxb[n * 3 + 2] = dxz;
        } else {
            unsafeAtomicAdd(&dxb[n * 3 + 0], dxx);
            unsafeAtomicAdd(&dxb[n * 3 + 1], dxy);
            unsafeAtomicAdd(&dxb[n * 3 + 2], dxz);
        }
    }
}

// ---------------------------------------------------------------- edge kernel: pipelined grid-stride
__global__ __launch_bounds__(256) void k_edge_pipe(
    const int* __restrict__ srcp, const int2* __restrict__ cpair, const int* __restrict__ ncptr,
    const float* __restrict__ xp,
    const float* __restrict__ P, const float* __restrict__ Q,
    const float* __restrict__ Wd,
    const bf16* __restrict__ We2h, const bf16* __restrict__ We2l,
    const float* __restrict__ be2, const float* __restrict__ Wx,
    float* __restrict__ agg, float* __restrict__ dxb)
{
    const int wv = threadIdx.x >> 6, lane = threadIdx.x & 63;
    const int g = lane >> 4, l15 = lane & 15;
    const int Wstride = EBLK * 4;
    const int NC = *ncptr;
    int c0 = blockIdx.x * 4 + wv;
    if (c0 >= NC) return;

    const float4* xp4 = reinterpret_cast<const float4*>(xp);
    const float4* Pf4 = reinterpret_cast<const float4*>(P);
    const float4* Qf4 = reinterpret_cast<const float4*>(Q);
    const v8bf* BHf = reinterpret_cast<const v8bf*>(We2h);
    const v8bf* BLf = reinterpret_cast<const v8bf*>(We2l);

    float wdv[2][8];
    UNPACK8(wdv[0], Wd + g * 8);
    UNPACK8(wdv[1], Wd + 32 + g * 8);
    float be2v[4], wxv[4];
#pragma unroll
    for (int nt = 0; nt < 4; nt++) { be2v[nt] = be2[l15 + 16 * nt]; wxv[nt] = Wx[l15 + 16 * nt]; }

    // ---- pipeline prologue (3-deep: payload@+1, src/xn@+2, meta@+3)
    int c1 = c0 + Wstride, c2 = c1 + Wstride, c3 = c2 + Wstride;
    int2 m0 = cpair[c0];
    int2 m1 = cpair[min(c1, NC - 1)];
    int2 m2 = cpair[min(c2, NC - 1)];
    int n0 = m0.x, eb0 = m0.y & 0xFFFFF, ct0 = (m0.y >> 20) & 31, sg0 = (m0.y >> 25) & 1;
    int n1 = m1.x, eb1 = m1.y & 0xFFFFF, ct1 = (m1.y >> 20) & 31, sg1 = (m1.y >> 25) & 1;
    int s0 = srcp[eb0 + min(l15, ct0 - 1)];
    int s1 = srcp[eb1 + min(l15, ct1 - 1)];
    float4 xn0 = xp4[n0], xn1 = xp4[n1];
    float4 xs0 = xp4[s0];
    float4 pw0[4], qv0[4];
    pw0[0] = Pf4[s0 * 16 + g * 2];     pw0[1] = Pf4[s0 * 16 + g * 2 + 1];
    pw0[2] = Pf4[s0 * 16 + 8 + g * 2]; pw0[3] = Pf4[s0 * 16 + 8 + g * 2 + 1];
    qv0[0] = Qf4[n0 * 16 + g * 2];     qv0[1] = Qf4[n0 * 16 + g * 2 + 1];
    qv0[2] = Qf4[n0 * 16 + 8 + g * 2]; qv0[3] = Qf4[n0 * 16 + 8 + g * 2 + 1];

    while (true) {
        float4 xs1 = xp4[s1];
        float4 pw1[4], qv1[4];
        pw1[0] = Pf4[s1 * 16 + g * 2];     pw1[1] = Pf4[s1 * 16 + g * 2 + 1];
        pw1[2] = Pf4[s1 * 16 + 8 + g * 2]; pw1[3] = Pf4[s1 * 16 + 8 + g * 2 + 1];
        qv1[0] = Qf4[n1 * 16 + g * 2];     qv1[1] = Qf4[n1 * 16 + g * 2 + 1];
        qv1[2] = Qf4[n1 * 16 + 8 + g * 2]; qv1[3] = Qf4[n1 * 16 + 8 + g * 2 + 1];
        int n2 = m2.x, eb2 = m2.y & 0xFFFFF, ct2 = (m2.y >> 20) & 31, sg2 = (m2.y >> 25) & 1;
        int s2 = srcp[eb2 + min(l15, ct2 - 1)];
        float4 xn2 = xp4[n2];
        int2 m3 = cpair[min(c3, NC - 1)];

        edge_compute(n0, ct0, sg0, xn0, xs0, pw0, qv0,
                     BHf, BLf, wdv, be2v, wxv, g, l15, lane, agg, dxb);

        c0 = c1; c1 = c2; c2 = c3; c3 += Wstride;
        n0 = n1; ct0 = ct1; sg0 = sg1; xn0 = xn1; xs0 = xs1;
#pragma unroll
        for (int j = 0; j < 4; j++) { pw0[j] = pw1[j]; qv0[j] = qv1[j]; }
        n1 = n2; ct1 = ct2; sg1 = sg2; s1 = s2; xn1 = xn2;
        m2 = m3;
        if (c0 >= NC) break;
    }
}

// ---------------------------------------------------------------- node update (MFMA, split-bf16)
// optional fusions: do_lat (latent), do_pq (next layer P/Q), do_out (output head, L3)
__global__ __launch_bounds__(256) void k_node_mfma(
    float* __restrict__ h, float* __restrict__ xp,
    float* __restrict__ agg, const float* __restrict__ dxb,
    const bf16* __restrict__ Wn1h, const bf16* __restrict__ Wn1l, const float* __restrict__ bn1,
    const bf16* __restrict__ Wn2h, const bf16* __restrict__ Wn2l, const float* __restrict__ bn2,
    int do_pq,
    const bf16* __restrict__ We1nh, const bf16* __restrict__ We1nl, const float* __restrict__ be1n,
    float* __restrict__ P, float* __restrict__ Q, float* __restrict__ dxbz,
    int do_lat,
    const bf16* __restrict__ Wlh, const bf16* __restrict__ Wll, const float* __restrict__ bl,
    const bf16* __restrict__ Wuh, const bf16* __restrict__ Wul, const float* __restrict__ bu,
    int do_out,
    const bf16* __restrict__ Woh, const bf16* __restrict__ Wol, const float* __restrict__ bo,
    float* __restrict__ out)
{
    __shared__ float sh[4][16][68];
    __shared__ float su[4][16][68];

    const int wv = threadIdx.x >> 6, lane = threadIdx.x & 63;
    const int g = lane >> 4, l15 = lane & 15;
    const int n0 = (blockIdx.x * 4 + wv) * 16;
    if (n0 >= NN) return;                      // no block barriers below -> safe

    const int nrow = n0 + l15;

    v8bf Ah[4], Al[4];
#pragma unroll
    for (int kh = 0; kh < 2; kh++) {
        float v[8];
        UNPACK8(v, h + nrow * 64 + kh * 32 + g * 8);
        *reinterpret_cast<float4*>(&sh[wv][l15][kh * 32 + g * 8])     = *reinterpret_cast<const float4*>(&v[0]);
        *reinterpret_cast<float4*>(&sh[wv][l15][kh * 32 + g * 8 + 4]) = *reinterpret_cast<const float4*>(&v[4]);
#pragma unroll
        for (int b = 0; b < 8; b++) {
            bf16 hi = (bf16)v[b];
            Ah[kh][b] = hi; Al[kh][b] = (bf16)(v[b] - (float)hi);
        }
    }
#pragma unroll
    for (int kh = 0; kh < 2; kh++) {
        float v[8];
        UNPACK8(v, agg + nrow * 64 + kh * 32 + g * 8);
#pragma unroll
        for (int b = 0; b < 8; b++) {
            bf16 hi = (bf16)v[b];
            Ah[2 + kh][b] = hi; Al[2 + kh][b] = (bf16)(v[b] - (float)hi);
        }
    }

    const v8bf* B1h = reinterpret_cast<const v8bf*>(Wn1h);
    const v8bf* B1l = reinterpret_cast<const v8bf*>(Wn1l);
    const v8bf* B2h = reinterpret_cast<const v8bf*>(Wn2h);
    const v8bf* B2l = reinterpret_cast<const v8bf*>(Wn2l);

    float bn1v[4];
#pragma unroll
    for (int nt = 0; nt < 4; nt++) bn1v[nt] = bn1[l15 + 16 * nt];
#pragma unroll
    for (int nt = 0; nt < 4; nt++) {
        v4f a = {0.f, 0.f, 0.f, 0.f};
#pragma unroll
        for (int kh = 0; kh < 4; kh++) {
            int fi = (kh * 4 + g) * 64 + l15 + 16 * nt;
            v8bf bh = B1h[fi], bl_ = B1l[fi];
            a = __builtin_amdgcn_mfma_f32_16x16x32_bf16(Ah[kh], bh, a, 0, 0, 0);
            a = __builtin_amdgcn_mfma_f32_16x16x32_bf16(Ah[kh], bl_, a, 0, 0, 0);
            a = __builtin_amdgcn_mfma_f32_16x16x32_bf16(Al[kh], bh, a, 0, 0, 0);
        }
#pragma unroll
        for (int i = 0; i < 4; i++)
            su[wv][g * 4 + i][l15 + 16 * nt] = silu_f(a[i] + bn1v[nt]);
    }
    asm volatile("s_waitcnt lgkmcnt(0)" ::: "memory");

    v8bf Uh[2], Ul[2];
#pragma unroll
    for (int kh = 0; kh < 2; kh++) {
        float v[8];
        *reinterpret_cast<float4*>(&v[0]) = *reinterpret_cast<const float4*>(&su[wv][l15][kh * 32 + g * 8]);
        *reinterpret_cast<float4*>(&v[4]) = *reinterpret_cast<const float4*>(&su[wv][l15][kh * 32 + g * 8 + 4]);
#pragma unroll
        for (int b = 0; b < 8; b++) {
            bf16 hi = (bf16)v[b];
            Uh[kh][b] = hi; Ul[kh][b] = (bf16)(v[b] - (float)hi);
        }
    }

    float bn2v[4];
#pragma unroll
    for (int nt = 0; nt < 4; nt++) bn2v[nt] = bn2[l15 + 16 * nt];
#pragma unroll
    for (int nt = 0; nt < 4; nt++) {
        v4f a = {0.f, 0.f, 0.f, 0.f};
#pragma unroll
        for (int kh = 0; kh < 2; kh++) {
            int fi = (kh * 4 + g) * 64 + l15 + 16 * nt;
            v8bf bh = B2h[fi], bl_ = B2l[fi];
            a = __builtin_amdgcn_mfma_f32_16x16x32_bf16(Uh[kh], bh, a, 0, 0, 0);
            a = __builtin_amdgcn_mfma_f32_16x16x32_bf16(Uh[kh], bl_, a, 0, 0, 0);
            a = __builtin_amdgcn_mfma_f32_16x16x32_bf16(Ul[kh], bh, a, 0, 0, 0);
        }
#pragma unroll
        for (int i = 0; i < 4; i++) {
            float hout = sh[wv][g * 4 + i][l15 + 16 * nt] + a[i] + bn2v[nt];
            if (!do_lat && !do_out) h[(n0 + g * 4 + i) * 64 + l15 + 16 * nt] = hout;
            if (do_pq || do_lat || do_out) sh[wv][g * 4 + i][l15 + 16 * nt] = hout;
        }
    }

    {
        int nd = lane >> 2, cc = lane & 3;
        if (cc < 3) {
            float xnew = xp[(n0 + nd) * 4 + cc] + dxb[(n0 + nd) * 3 + cc] * (1.f / 16.f);
            if (do_out) {
                out[(n0 + nd) * 19 + 16 + cc] = xnew;
            } else {
                xp[(n0 + nd) * 4 + cc] = xnew;
                if (do_pq) dxbz[(n0 + nd) * 3 + cc] = 0.f;
            }
        }
    }

    if (do_lat) {
        asm volatile("s_waitcnt lgkmcnt(0)" ::: "memory");
        v8bf Hh[2], Hl[2];
#pragma unroll
        for (int kh = 0; kh < 2; kh++) {
            float v[8];
            *reinterpret_cast<float4*>(&v[0]) = *reinterpret_cast<const float4*>(&sh[wv][l15][kh * 32 + g * 8]);
            *reinterpret_cast<float4*>(&v[4]) = *reinterpret_cast<const float4*>(&sh[wv][l15][kh * 32 + g * 8 + 4]);
#pragma unroll
            for (int b = 0; b < 8; b++) {
                bf16 hi = (bf16)v[b];
                Hh[kh][b] = hi; Hl[kh][b] = (bf16)(v[b] - (float)hi);
            }
        }
        const v8bf* BLh = reinterpret_cast<const v8bf*>(Wlh);
        const v8bf* BLl = reinterpret_cast<const v8bf*>(Wll);
#pragma unroll
        for (int nt = 0; nt < 2; nt++) {
            v4f a = {0.f, 0.f, 0.f, 0.f};
#pragma unroll
            for (int kh = 0; kh < 2; kh++) {
                int fi = (kh * 4 + g) * 32 + l15 + 16 * nt;
                v8bf bh = BLh[fi], bl_ = BLl[fi];
                a = __builtin_amdgcn_mfma_f32_16x16x32_bf16(Hh[kh], bh, a, 0, 0, 0);
                a = __builtin_amdgcn_mfma_f32_16x16x32_bf16(Hh[kh], bl_, a, 0, 0, 0);
                a = __builtin_amdgcn_mfma_f32_16x16x32_bf16(Hl[kh], bh, a, 0, 0, 0);
            }
            float blv = bl[l15 + 16 * nt];
#pragma unroll
            for (int i = 0; i < 4; i++)
                su[wv][g * 4 + i][l15 + 16 * nt] = a[i] + blv;
        }
        asm volatile("s_waitcnt lgkmcnt(0)" ::: "memory");

        v8bf Zh, Zl;
        {
            float v[8];
            *reinterpret_cast<float4*>(&v[0]) = *reinterpret_cast<const float4*>(&su[wv][l15][g * 8]);
            *reinterpret_cast<float4*>(&v[4]) = *reinterpret_cast<const float4*>(&su[wv][l15][g * 8 + 4]);
#pragma unroll
            for (int b = 0; b < 8; b++) {
                bf16 hi = (bf16)v[b];
                Zh[b] = hi; Zl[b] = (bf16)(v[b] - (float)hi);
            }
        }
        const v8bf* BUh = reinterpret_cast<const v8bf*>(Wuh);
        const v8bf* BUl = reinterpret_cast<const v8bf*>(Wul);
#pragma unroll
        for (int nt = 0; nt < 4; nt++) {
            v4f a = {0.f, 0.f, 0.f, 0.f};
            int fi = g * 64 + l15 + 16 * nt;
            v8bf bh = BUh[fi], bl_ = BUl[fi];
            a = __builtin_amdgcn_mfma_f32_16x16x32_bf16(Zh, bh, a, 0, 0, 0);
            a = __builtin_amdgcn_mfma_f32_16x16x32_bf16(Zh, bl_, a, 0, 0, 0);
            a = __builtin_amdgcn_mfma_f32_16x16x32_bf16(Zl, bh, a, 0, 0, 0);
            float buv = bu[l15 + 16 * nt];
#pragma unroll
            for (int i = 0; i < 4; i++) {
                float hout = a[i] + buv;
                h[(n0 + g * 4 + i) * 64 + l15 + 16 * nt] = hout;
                sh[wv][g * 4 + i][l15 + 16 * nt] = hout;
            }
        }
    }

    if (do_pq) {
        asm volatile("s_waitcnt lgkmcnt(0)" ::: "memory");
        v8bf Hh[2], Hl[2];
#pragma unroll
        for (int kh = 0; kh < 2; kh++) {
            float v[8];
            *reinterpret_cast<float4*>(&v[0]) = *reinterpret_cast<const float4*>(&sh[wv][l15][kh * 32 + g * 8]);
            *reinterpret_cast<float4*>(&v[4]) = *reinterpret_cast<const float4*>(&sh[wv][l15][kh * 32 + g * 8 + 4]);
#pragma unroll
            for (int b = 0; b < 8; b++) {
                bf16 hi = (bf16)v[b];
                Hh[kh][b] = hi; Hl[kh][b] = (bf16)(v[b] - (float)hi);
            }
        }
        const v8bf* Bh = reinterpret_cast<const v8bf*>(We1nh);
        const v8bf* Bl = reinterpret_cast<const v8bf*>(We1nl);
        float be1v[4];
#pragma unroll
        for (int nt = 0; nt < 4; nt++) be1v[nt] = be1n[l15 + 16 * nt];
#pragma unroll
        for (int nt = 0; nt < 4; nt++) {
            v4f ap = {0.f,0.f,0.f,0.f}, aq = {0.f,0.f,0.f,0.f};
#pragma unroll
            for (int kh = 0; kh < 2; kh++) {
                int fiP = (kh * 4 + g) * 64 + l15 + 16 * nt;
                int fiQ = ((kh + 2) * 4 + g) * 64 + l15 + 16 * nt;
                v8bf bph = Bh[fiP], bpl = Bl[fiP];
                v8bf bqh = Bh[fiQ], bql = Bl[fiQ];
                ap = __builtin_amdgcn_mfma_f32_16x16x32_bf16(Hh[kh], bph, ap, 0, 0, 0);
                ap = __builtin_amdgcn_mfma_f32_16x16x32_bf16(Hh[kh], bpl, ap, 0, 0, 0);
                ap = __builtin_amdgcn_mfma_f32_16x16x32_bf16(Hl[kh], bph, ap, 0, 0, 0);
                aq = __builtin_amdgcn_mfma_f32_16x16x32_bf16(Hh[kh], bqh, aq, 0, 0, 0);
                aq = __builtin_amdgcn_mfma_f32_16x16x32_bf16(Hh[kh], bql, aq, 0, 0, 0);
                aq = __builtin_amdgcn_mfma_f32_16x16x32_bf16(Hl[kh], bqh, aq, 0, 0, 0);
            }
#pragma unroll
            for (int i = 0; i < 4; i++) {
                int ro = (n0 + g * 4 + i) * 64 + l15 + 16 * nt;
                P[ro] = ap[i] + be1v[nt];
                Q[ro] = aq[i];
                agg[ro] = 0.f;
            }
        }
    }

    if (do_out) {
        asm volatile("s_waitcnt lgkmcnt(0)" ::: "memory");
        v8bf Hh[2], Hl[2];
#pragma unroll
        for (int kh = 0; kh < 2; kh++) {
            float v[8];
            *reinterpret_cast<float4*>(&v[0]) = *reinterpret_cast<const float4*>(&sh[wv][l15][kh * 32 + g * 8]);
            *reinterpret_cast<float4*>(&v[4]) = *reinterpret_cast<const float4*>(&sh[wv][l15][kh * 32 + g * 8 + 4]);
#pragma unroll
            for (int b = 0; b < 8; b++) {
                bf16 hi = (bf16)v[b];
                Hh[kh][b] = hi; Hl[kh][b] = (bf16)(v[b] - (float)hi);
            }
        }
        const v8bf* BOh = reinterpret_cast<const v8bf*>(Woh);
        const v8bf* BOl = reinterpret_cast<const v8bf*>(Wol);
        float bov = bo[l15];
        v4f a = {0.f, 0.f, 0.f, 0.f};
#pragma unroll
        for (int kh = 0; kh < 2; kh++) {
            int fi = (kh * 4 + g) * 16 + l15;
            v8bf bh = BOh[fi], bl_ = BOl[fi];
            a = __builtin_amdgcn_mfma_f32_16x16x32_bf16(Hh[kh], bh, a, 0, 0, 0);
            a = __builtin_amdgcn_mfma_f32_16x16x32_bf16(Hh[kh], bl_, a, 0, 0, 0);
            a = __builtin_amdgcn_mfma_f32_16x16x32_bf16(Hl[kh], bh, a, 0, 0, 0);
        }
#pragma unroll
        for (int i = 0; i < 4; i++)
            out[(n0 + g * 4 + i) * 19 + l15] = a[i] + bov;
    }
}

extern "C" void kernel_launch(void* const* d_in, const int* in_sizes, int n_in,
                              void* d_out, int out_size, void* d_ws, size_t ws_size,
                              hipStream_t stream)
{
    const float* h_in  = (const float*)d_in[0];
    const float* x_in  = (const float*)d_in[1];
    const int*   ei    = (const int*)d_in[2];
    const float* W_emb = (const float*)d_in[3];
    const float* b_emb = (const float*)d_in[4];
    const float* W_lat = (const float*)d_in[5];
    const float* b_lat = (const float*)d_in[6];
    const float* W_up  = (const float*)d_in[7];
    const float* b_up  = (const float*)d_in[8];
    const float* W_out = (const float*)d_in[9];
    const float* b_out = (const float*)d_in[10];
    const float* encp[9]; const float* decp[9];
    for (int i = 0; i < 9; i++) { encp[i] = (const float*)d_in[11 + i]; decp[i] = (const float*)d_in[20 + i]; }

    const int* src = ei;
    const int* dst = ei + NE;

    // workspace layout
    float* ws  = (float*)d_ws;
    float* h   = ws;                       // NN*64
    float* xp  = h + NN * 64;              // NN*4
    float* P   = xp + NN * 4;              // NN*64
    float* Q   = P + NN * 64;              // NN*64
    float* agg = Q + NN * 64;              // NN*64
    float* dxb = agg + NN * 64;            // NN*3
    int* off   = (int*)(dxb + NN * 3);     // NN+1
    int* cur   = off + (NN + 1);           // NN+1
    int* bsum  = cur + (NN + 1);           // 2*SCB
    int* bbase = bsum + 2 * SCB;           // 2*SCB
    int* srcp  = bbase + 2 * SCB;          // NE
    int* ncptr = srcp + NE;                // 1 (+1 pad for int2 align)
    int2* cpair = (int2*)(ncptr + 2);      // MAXC
    bf16* We1h = (bf16*)(cpair + MAXC);    // 4*8192
    bf16* We1l = We1h + 4 * 8192;
    bf16* We2h = We1l + 4 * 8192;          // 4*4096
    bf16* We2l = We2h + 4 * 4096;
    bf16* Wn1h = We2l + 4 * 4096;          // 4*8192
    bf16* Wn1l = Wn1h + 4 * 8192;
    bf16* Wn2h = Wn1l + 4 * 8192;          // 4*4096
    bf16* Wn2l = Wn2h + 4 * 4096;
    bf16* Wlh  = Wn2l + 4 * 4096;          // 2048
    bf16* Wll  = Wlh + 2048;
    bf16* Wuh  = Wll + 2048;               // 2048
    bf16* Wul  = Wuh + 2048;
    bf16* Wembh = Wul + 2048;              // 2048 (K padded to 32)
    bf16* Wembl = Wembh + 2048;
    bf16* Wouth = Wembl + 2048;            // 1024
    bf16* Woutl = Wouth + 1024;

    // ---- one-time: CSR by dst, chunk meta (fused), weight prep
    hipMemsetAsync(cur, 0, (NN + 1) * sizeof(int), stream);
    k_hist<<<NE / 256, 256, 0, stream>>>(dst, cur);
    k_blocksum<<<SCB, 256, 0, stream>>>(cur, bsum);
    k_scanbase<<<1, 256, 0, stream>>>(bsum, bbase, ncptr);
    k_applyscan<<<SCB, 256, 0, stream>>>(cur, bbase, off, cur, cpair);
    k_scatter<<<NE / 256, 256, 0, stream>>>(dst, src, cur, srcp);
    k_prep_all<<<412, 256, 0, stream>>>(encp[0], decp[0], encp[2], decp[2],
                                        encp[5], decp[5], encp[7], decp[7],
                                        W_lat, W_up, W_emb, W_out,
                                        We1h, We1l, We2h, We2l, Wn1h, Wn1l, Wn2h, Wn2l,
                                        Wlh, Wll, Wuh, Wul, Wembh, Wembl, Wouth, Woutl);

    const int NODE_GRID = (NN / 16 + 3) / 4;

    // L0: embed + P/Q fused
    k_pq_mfma<<<NODE_GRID, 256, 0, stream>>>(h_in, x_in, Wembh, Wembl, b_emb, h, xp,
                                             We1h, We1l, encp[1], P, Q, agg, dxb);

    for (int L = 0; L < 4; ++L) {
        const float** pp = (L < 2) ? encp : decp;
        int li = (L < 2) ? L : L - 2;
        const float* We1 = pp[0] + li * 129 * 64;
        const float* be2 = pp[3] + li * 64;
        const float* Wx  = pp[4] + li * 64;
        const float* bn1 = pp[6] + li * 64;
        const float* bn2 = pp[8] + li * 64;

        k_edge_pipe<<<EBLK, 256, 0, stream>>>(srcp, cpair, ncptr,
                                              xp, P, Q, We1 + 128 * 64,
                                              We2h + L * 4096, We2l + L * 4096,
                                              be2, Wx, agg, dxb);

        int do_pq = (L < 3) ? 1 : 0;
        int do_lat = (L == 1) ? 1 : 0;
        int do_out = (L == 3) ? 1 : 0;
        int Ln = L + 1;   // packed order enc0,enc1,dec0,dec1
        const float* be1n = bn1;
        if (do_pq) be1n = (Ln < 2 ? encp[1] : decp[1]) + ((Ln < 2 ? Ln : Ln - 2)) * 64;

        k_node_mfma<<<NODE_GRID, 256, 0, stream>>>(h, xp, agg, dxb,
                                                   Wn1h + L * 8192, Wn1l + L * 8192, bn1,
                                                   Wn2h + L * 4096, Wn2l + L * 4096, bn2,
                                                   do_pq,
                                                   We1h + (do_pq ? Ln : 0) * 8192,
                                                   We1l + (do_pq ? Ln : 0) * 8192, be1n,
                                                   P, Q, dxb,
                                                   do_lat, Wlh, Wll, b_lat, Wuh, Wul, b_up,
                                                   do_out, Wouth, Woutl, b_out, (float*)d_out);
    }
}